// Round 11
// baseline (390.352 us; speedup 1.0000x reference)
//
#include <hip/hip_runtime.h>
#include <hip/hip_bf16.h>
#include <math.h>

#define HIDDEN 1024
#define NEXP 8
#define TOPK 2
#define INTER 1408
#define SINTER 2816
#define NTOK 4096
#define NROWS (NTOK * TOPK) /* 8192 routed rows */
#define NPANEL 10           /* 8 routed + 2 shared halves */
#define TROWS 16384         /* NROWS + 2*NTOK */
#define MAXT 136            /* max (panel, m-block) tasks */

typedef unsigned short ushort_t;
typedef __attribute__((ext_vector_type(8))) short short8;
typedef __attribute__((ext_vector_type(4))) float f32x4;

__device__ __forceinline__ ushort_t f2bf(float f) {
    unsigned int b = __float_as_uint(f);
    unsigned int r = (b + 0x7FFFu + ((b >> 16) & 1u)) >> 16;
    return (ushort_t)r;
}
__device__ __forceinline__ float bf2f(ushort_t u) {
    return __uint_as_float(((unsigned int)u) << 16);
}
__device__ __forceinline__ float silu_f(float g) {
    return g * (1.0f / (1.0f + __expf(-g)));
}
__device__ __forceinline__ int imin(int a, int b) { return a < b ? a : b; }

#define GLDS16(gp, lp) __builtin_amdgcn_global_load_lds(                     \
    (const __attribute__((address_space(1))) void*)(gp),                     \
    (__attribute__((address_space(3))) void*)(lp), 16, 0, 0)

// ---------------- fp32 -> bf16 elementwise (x) ----------------
__global__ void conv_x(const float* __restrict__ src, ushort_t* __restrict__ dst) {
    int i = (blockIdx.x * 256 + threadIdx.x) * 4;
    float4 v = *reinterpret_cast<const float4*>(&src[i]);
    union { ushort_t h[4]; unsigned long long ll; } p;
    p.h[0] = f2bf(v.x); p.h[1] = f2bf(v.y); p.h[2] = f2bf(v.z); p.h[3] = f2bf(v.w);
    *reinterpret_cast<unsigned long long*>(&dst[i]) = p.ll;
}

// ---- fp32 [R][C] -> bf16 [C][R] transpose-convert, 64r x 32c tiles, ------
// 16B-vectorized bf16 stores.
__global__ __launch_bounds__(256) void tconv64(const float* __restrict__ src,
                                               ushort_t* __restrict__ dst,
                                               int R, int C, long sstride,
                                               long dstride) {
    src += (size_t)blockIdx.z * sstride;
    dst += (size_t)blockIdx.z * dstride;
    __shared__ float tile[32][65];
    int ct = blockIdx.x * 32, rt = blockIdx.y * 64;
    int j = threadIdx.x;
    {
        int r = j >> 2;            // 0..63
        int c0 = (j & 3) * 8;      // 0,8,16,24
        const float* s = &src[(size_t)(rt + r) * C + ct + c0];
        float4 v0 = *reinterpret_cast<const float4*>(s);
        float4 v1 = *reinterpret_cast<const float4*>(s + 4);
        tile[c0 + 0][r] = v0.x; tile[c0 + 1][r] = v0.y;
        tile[c0 + 2][r] = v0.z; tile[c0 + 3][r] = v0.w;
        tile[c0 + 4][r] = v1.x; tile[c0 + 5][r] = v1.y;
        tile[c0 + 6][r] = v1.z; tile[c0 + 7][r] = v1.w;
    }
    __syncthreads();
    {
        int c = j >> 3;            // 0..31
        int r0 = (j & 7) * 8;      // 0..56
        union { ushort_t h[8]; short8 v; } p;
#pragma unroll
        for (int i = 0; i < 8; i++) p.h[i] = f2bf(tile[c][r0 + i]);
        *reinterpret_cast<short8*>(&dst[(size_t)(ct + c) * R + rt + r0]) = p.v;
    }
}

// ---------------- gate: logits -> softmax -> top2 -> normalized weights ----
__global__ void gate_kernel(const float* __restrict__ x, const float* __restrict__ gw,
                            int* __restrict__ top_i, float* __restrict__ top_w) {
    int t = blockIdx.x;
    int lane = threadIdx.x;
    const float* xr = x + (size_t)t * HIDDEN;
    float acc[NEXP];
#pragma unroll
    for (int e = 0; e < NEXP; e++) acc[e] = 0.f;
    for (int j = 0; j < HIDDEN / 64; j++) {
        float xv = xr[lane + 64 * j];
#pragma unroll
        for (int e = 0; e < NEXP; e++)
            acc[e] = fmaf(xv, gw[e * HIDDEN + lane + 64 * j], acc[e]);
    }
#pragma unroll
    for (int e = 0; e < NEXP; e++) {
        float v = acc[e];
        for (int off = 32; off > 0; off >>= 1) v += __shfl_xor(v, off, 64);
        acc[e] = v;
    }
    if (lane == 0) {
        float mx = acc[0];
        for (int e = 1; e < NEXP; e++) mx = fmaxf(mx, acc[e]);
        float s[NEXP];
        float sum = 0.f;
        for (int e = 0; e < NEXP; e++) { s[e] = __expf(acc[e] - mx); sum += s[e]; }
        float inv = 1.0f / sum;
        for (int e = 0; e < NEXP; e++) s[e] *= inv;
        int e0 = 0;
        for (int e = 1; e < NEXP; e++) if (s[e] > s[e0]) e0 = e;
        int e1 = -1;
        for (int e = 0; e < NEXP; e++) {
            if (e == e0) continue;
            if (e1 < 0 || s[e] > s[e1]) e1 = e;
        }
        float w0 = s[e0], w1 = s[e1];
        float denom = w0 + w1 + 1e-20f;
        top_i[t * 2 + 0] = e0;
        top_i[t * 2 + 1] = e1;
        top_w[t * 2 + 0] = w0 / denom;
        top_w[t * 2 + 1] = w1 / denom;
    }
}

// ---------------- routing bookkeeping ----------------
__global__ void assign_kernel(const int* __restrict__ top_i, int* __restrict__ cnt,
                              int* __restrict__ rnk) {
    int j = blockIdx.x * blockDim.x + threadIdx.x;
    if (j < NROWS) rnk[j] = atomicAdd(&cnt[top_i[j]], 1);
}

// builds offsets AND the dense (panel, m-block) task table
__global__ void scan_kernel(const int* __restrict__ cnt, int* __restrict__ offs2,
                            int* __restrict__ cnt2, int* __restrict__ task_pm) {
    if (threadIdx.x == 0) {
        int o = 0;
        for (int e = 0; e < NEXP; e++) { offs2[e] = o; cnt2[e] = cnt[e]; o += cnt[e]; }
        offs2[8] = NROWS;          cnt2[8] = NTOK;
        offs2[9] = NROWS + NTOK;   cnt2[9] = NTOK;
        offs2[10] = TROWS;
        int t = 0;
        for (int e = 0; e < NPANEL; e++)
            for (int m0 = 0; m0 < cnt2[e]; m0 += 128)
                task_pm[t++] = (e << 16) | (m0 >> 7);
        for (; t < MAXT; t++) task_pm[t] = -1;
    }
}

__global__ void fill_kernel(const int* __restrict__ top_i, const float* __restrict__ top_w,
                            const int* __restrict__ rnk, const int* __restrict__ offs2,
                            int* __restrict__ tok_of_row, float* __restrict__ w_of_row,
                            int* __restrict__ inv_row) {
    int j = blockIdx.x * blockDim.x + threadIdx.x;
    if (j < NROWS) {
        int row = offs2[top_i[j]] + rnk[j];
        tok_of_row[row] = j;  // token = j>>1
        w_of_row[row] = top_w[j];
        inv_row[j] = row;
    }
}

__global__ void fill_shared(int* __restrict__ tok_of_row) {
    int j = blockIdx.x * blockDim.x + threadIdx.x;  // 0..8191
    tok_of_row[NROWS + j] = (j & (NTOK - 1)) << 1;  // token = j mod 4096
}

// ============ GEMM 1: act = silu(x@Wg)*(x@Wu) ==============================
// 256 thr / 4 waves (2x2), tile 128Mx128N over BOTH Wg and Wu, BK=64
// (2 k-subtiles of 32 -> 64 MFMA per barrier window, half as many barrier
// drains), single-buffer 48KB fragment-ordered LDS (conflict-free), dense
// task-table dispatch, XCD-chunked swizzle over dense 1-D grid.
__global__ __launch_bounds__(256, 2) void gemm_gu(
    const ushort_t* __restrict__ xb, const ushort_t* __restrict__ WgT,
    const ushort_t* __restrict__ WuT, ushort_t* __restrict__ act,
    const int* __restrict__ tok_of_row, const int* __restrict__ offs2,
    const int* __restrict__ cnt2, const int* __restrict__ task_pm) {
    int T = gridDim.x;  // MAXT * (INTER/128), divisible by 8
    int orig = blockIdx.x;
    int logical = (orig & 7) * (T >> 3) + (orig >> 3);
    int task = logical % MAXT;
    int nidx = logical / MAXT;
    int tk = task_pm[task];
    if (tk < 0) return;
    int e = tk >> 16;
    int m0 = (tk & 0xffff) << 7;
    int mcnt = cnt2[e];
    int base = offs2[e];
    int n0 = nidx * 128;
    const ushort_t* Bg = WgT + (size_t)e * INTER * HIDDEN;
    const ushort_t* Bu = WuT + (size_t)e * INTER * HIDDEN;

    // [rowblk 0..7][ksub 0..1][512]  (16KB each)
    __shared__ short As[8 * 1024];
    __shared__ short Bgs[8 * 1024];
    __shared__ short Bus[8 * 1024];

    int tid = threadIdx.x;
    int wave = tid >> 6, lane = tid & 63;
    int wr = wave >> 1, wc = wave & 1;  // 2x2 waves, each 64x64
    int lr = lane & 15;
    int kq = (lane >> 4) * 8;  // k-chunk of this lane (8 bf16 = 16B)

    int r0 = m0 + 32 * wave + lr, r1 = r0 + 16;
    int rr0 = base + imin(r0, mcnt - 1);
    int rr1 = base + imin(r1, mcnt - 1);
    const ushort_t* srcA0 = xb + (size_t)(tok_of_row[rr0] >> 1) * HIDDEN + kq;
    const ushort_t* srcA1 = xb + (size_t)(tok_of_row[rr1] >> 1) * HIDDEN + kq;
    const ushort_t* srcBg0 = Bg + (size_t)(n0 + 32 * wave + lr) * HIDDEN + kq;
    const ushort_t* srcBg1 = srcBg0 + (size_t)16 * HIDDEN;
    const ushort_t* srcBu0 = Bu + (size_t)(n0 + 32 * wave + lr) * HIDDEN + kq;
    const ushort_t* srcBu1 = srcBu0 + (size_t)16 * HIDDEN;

    f32x4 accG[4][4] = {};
    f32x4 accU[4][4] = {};

    for (int k0 = 0; k0 < HIDDEN; k0 += 64) {
        GLDS16(srcA0 + k0,      &As[(2 * wave) * 1024]);
        GLDS16(srcA0 + k0 + 32, &As[(2 * wave) * 1024 + 512]);
        GLDS16(srcA1 + k0,      &As[(2 * wave + 1) * 1024]);
        GLDS16(srcA1 + k0 + 32, &As[(2 * wave + 1) * 1024 + 512]);
        GLDS16(srcBg0 + k0,      &Bgs[(2 * wave) * 1024]);
        GLDS16(srcBg0 + k0 + 32, &Bgs[(2 * wave) * 1024 + 512]);
        GLDS16(srcBg1 + k0,      &Bgs[(2 * wave + 1) * 1024]);
        GLDS16(srcBg1 + k0 + 32, &Bgs[(2 * wave + 1) * 1024 + 512]);
        GLDS16(srcBu0 + k0,      &Bus[(2 * wave) * 1024]);
        GLDS16(srcBu0 + k0 + 32, &Bus[(2 * wave) * 1024 + 512]);
        GLDS16(srcBu1 + k0,      &Bus[(2 * wave + 1) * 1024]);
        GLDS16(srcBu1 + k0 + 32, &Bus[(2 * wave + 1) * 1024 + 512]);
        __syncthreads();
#pragma unroll
        for (int s = 0; s < 2; s++) {
            short8 a[4], bg[4], bu[4];
#pragma unroll
            for (int mi = 0; mi < 4; mi++)
                a[mi] = *reinterpret_cast<const short8*>(
                    &As[(wr * 4 + mi) * 1024 + s * 512 + lane * 8]);
#pragma unroll
            for (int ni = 0; ni < 4; ni++) {
                bg[ni] = *reinterpret_cast<const short8*>(
                    &Bgs[(wc * 4 + ni) * 1024 + s * 512 + lane * 8]);
                bu[ni] = *reinterpret_cast<const short8*>(
                    &Bus[(wc * 4 + ni) * 1024 + s * 512 + lane * 8]);
            }
#pragma unroll
            for (int mi = 0; mi < 4; mi++)
#pragma unroll
                for (int ni = 0; ni < 4; ni++) {
                    accG[mi][ni] = __builtin_amdgcn_mfma_f32_16x16x32_bf16(
                        a[mi], bg[ni], accG[mi][ni], 0, 0, 0);
                    accU[mi][ni] = __builtin_amdgcn_mfma_f32_16x16x32_bf16(
                        a[mi], bu[ni], accU[mi][ni], 0, 0, 0);
                }
        }
        __syncthreads();
    }

    // epilogue: silu(g)*u -> bf16 act (compact rows)
#pragma unroll
    for (int mi = 0; mi < 4; mi++) {
#pragma unroll
        for (int r = 0; r < 4; r++) {
            int gm = m0 + wr * 64 + mi * 16 + (lane >> 4) * 4 + r;
            if (gm < mcnt) {
#pragma unroll
                for (int ni = 0; ni < 4; ni++) {
                    int col = n0 + wc * 64 + ni * 16 + lr;
                    float g = accG[mi][ni][r], u = accU[mi][ni][r];
                    act[(size_t)(base + gm) * INTER + col] = f2bf(silu_f(g) * u);
                }
            }
        }
    }
}

// ============ GEMM 2: part = act @ Wd (compact rows, plain bf16 stores) ====
// Tile 128Mx256N, BK=64 (64 MFMA per window), single-buffer 48KB LDS,
// fragment-ordered, dense task-table dispatch, XCD swizzle. NO atomics.
__global__ __launch_bounds__(256, 2) void gemm_down(
    const ushort_t* __restrict__ act, const ushort_t* __restrict__ WdT,
    ushort_t* __restrict__ part, const int* __restrict__ offs2,
    const int* __restrict__ cnt2, const int* __restrict__ task_pm) {
    int T = gridDim.x;  // MAXT * (HIDDEN/256)
    int orig = blockIdx.x;
    int logical = (orig & 7) * (T >> 3) + (orig >> 3);
    int task = logical % MAXT;
    int nidx = logical / MAXT;
    int tk = task_pm[task];
    if (tk < 0) return;
    int e = tk >> 16;
    int m0 = (tk & 0xffff) << 7;
    int mcnt = cnt2[e];
    int base = offs2[e];
    int n0 = nidx * 256;
    const ushort_t* Bd = WdT + (size_t)e * HIDDEN * INTER;

    __shared__ short As[8 * 1024];   // 16KB
    __shared__ short Bs[16 * 1024];  // 32KB

    int tid = threadIdx.x;
    int wave = tid >> 6, lane = tid & 63;
    int wr = wave >> 1, wc = wave & 1;  // each wave: 64M x 128N
    int lr = lane & 15;
    int kq = (lane >> 4) * 8;

    // A rows compact; max staged row = base+m0+127 <= TROWS-1.
    const ushort_t* srcA0 = act + (size_t)(base + m0 + 32 * wave + lr) * INTER + kq;
    const ushort_t* srcA1 = srcA0 + (size_t)16 * INTER;
    const ushort_t* srcB0 = Bd + (size_t)(n0 + 64 * wave + lr) * INTER + kq;
    const ushort_t* srcB1 = srcB0 + (size_t)16 * INTER;
    const ushort_t* srcB2 = srcB0 + (size_t)32 * INTER;
    const ushort_t* srcB3 = srcB0 + (size_t)48 * INTER;

    f32x4 acc[4][8] = {};

    for (int k0 = 0; k0 < INTER; k0 += 64) {
        GLDS16(srcA0 + k0,      &As[(2 * wave) * 1024]);
        GLDS16(srcA0 + k0 + 32, &As[(2 * wave) * 1024 + 512]);
        GLDS16(srcA1 + k0,      &As[(2 * wave + 1) * 1024]);
        GLDS16(srcA1 + k0 + 32, &As[(2 * wave + 1) * 1024 + 512]);
        GLDS16(srcB0 + k0,      &Bs[(4 * wave) * 1024]);
        GLDS16(srcB0 + k0 + 32, &Bs[(4 * wave) * 1024 + 512]);
        GLDS16(srcB1 + k0,      &Bs[(4 * wave + 1) * 1024]);
        GLDS16(srcB1 + k0 + 32, &Bs[(4 * wave + 1) * 1024 + 512]);
        GLDS16(srcB2 + k0,      &Bs[(4 * wave + 2) * 1024]);
        GLDS16(srcB2 + k0 + 32, &Bs[(4 * wave + 2) * 1024 + 512]);
        GLDS16(srcB3 + k0,      &Bs[(4 * wave + 3) * 1024]);
        GLDS16(srcB3 + k0 + 32, &Bs[(4 * wave + 3) * 1024 + 512]);
        __syncthreads();
#pragma unroll
        for (int s = 0; s < 2; s++) {
            short8 a[4], b[8];
#pragma unroll
            for (int mi = 0; mi < 4; mi++)
                a[mi] = *reinterpret_cast<const short8*>(
                    &As[(wr * 4 + mi) * 1024 + s * 512 + lane * 8]);
#pragma unroll
            for (int ni = 0; ni < 8; ni++)
                b[ni] = *reinterpret_cast<const short8*>(
                    &Bs[(wc * 8 + ni) * 1024 + s * 512 + lane * 8]);
#pragma unroll
            for (int mi = 0; mi < 4; mi++)
#pragma unroll
                for (int ni = 0; ni < 8; ni++)
                    acc[mi][ni] = __builtin_amdgcn_mfma_f32_16x16x32_bf16(
                        a[mi], b[ni], acc[mi][ni], 0, 0, 0);
        }
        __syncthreads();
    }

#pragma unroll
    for (int mi = 0; mi < 4; mi++) {
#pragma unroll
        for (int r = 0; r < 4; r++) {
            int gm = m0 + wr * 64 + mi * 16 + (lane >> 4) * 4 + r;
            if (gm < mcnt) {
#pragma unroll
                for (int ni = 0; ni < 8; ni++) {
                    int col = n0 + wc * 128 + ni * 16 + lr;
                    part[(size_t)(base + gm) * HIDDEN + col] = f2bf(acc[mi][ni][r]);
                }
            }
        }
    }
}

// ============ combine: out[t] = w0*part[r0] + w1*part[r1] + part[s8] + part[s9]
__global__ __launch_bounds__(256) void combine_kernel(
    const ushort_t* __restrict__ part, const int* __restrict__ inv_row,
    const float* __restrict__ w_of_row, float* __restrict__ out) {
    int t = blockIdx.x;
    int c = threadIdx.x * 4;
    int r0 = inv_row[2 * t], r1 = inv_row[2 * t + 1];
    float w0 = w_of_row[r0], w1 = w_of_row[r1];
    ushort4 a0 = *reinterpret_cast<const ushort4*>(&part[(size_t)r0 * HIDDEN + c]);
    ushort4 a1 = *reinterpret_cast<const ushort4*>(&part[(size_t)r1 * HIDDEN + c]);
    ushort4 a2 = *reinterpret_cast<const ushort4*>(&part[((size_t)NROWS + t) * HIDDEN + c]);
    ushort4 a3 = *reinterpret_cast<const ushort4*>(&part[((size_t)NROWS + NTOK + t) * HIDDEN + c]);
    float4 o;
    o.x = w0 * bf2f(a0.x) + w1 * bf2f(a1.x) + bf2f(a2.x) + bf2f(a3.x);
    o.y = w0 * bf2f(a0.y) + w1 * bf2f(a1.y) + bf2f(a2.y) + bf2f(a3.y);
    o.z = w0 * bf2f(a0.z) + w1 * bf2f(a1.z) + bf2f(a2.z) + bf2f(a3.z);
    o.w = w0 * bf2f(a0.w) + w1 * bf2f(a1.w) + bf2f(a2.w) + bf2f(a3.w);
    *reinterpret_cast<float4*>(&out[(size_t)t * HIDDEN + c]) = o;
}

extern "C" void kernel_launch(void* const* d_in, const int* in_sizes, int n_in,
                              void* d_out, int out_size, void* d_ws, size_t ws_size,
                              hipStream_t stream) {
    const float* x   = (const float*)d_in[0];
    const float* gw  = (const float*)d_in[1];
    const float* wg  = (const float*)d_in[2];
    const float* wu  = (const float*)d_in[3];
    const float* wd  = (const float*)d_in[4];
    const float* swg = (const float*)d_in[5];
    const float* swu = (const float*)d_in[6];
    const float* swd = (const float*)d_in[7];
    float* out = (float*)d_out;

    // ---- workspace layout (bf16 buffers first, 16B-aligned) ----
    const size_t XB   = (size_t)NTOK * HIDDEN;
    const size_t WPAN = (size_t)NPANEL * INTER * HIDDEN;
    const size_t ACT  = (size_t)TROWS * INTER;
    const size_t PART = (size_t)TROWS * HIDDEN;
    ushort_t* xb   = (ushort_t*)d_ws;
    ushort_t* wgT  = xb + XB;
    ushort_t* wuT  = wgT + WPAN;
    ushort_t* wdT  = wuT + WPAN;
    ushort_t* act  = wdT + WPAN;
    ushort_t* part = act + ACT;
    int* ib = (int*)(part + PART);
    int* top_i      = ib;                 // NROWS
    int* rnk        = ib + NROWS;         // NROWS
    int* cnt        = ib + 2 * NROWS;     // 8
    int* offs2      = ib + 2 * NROWS + 8; // 16
    int* cnt2       = offs2 + 16;         // 16
    int* task_pm    = cnt2 + 16;          // MAXT
    int* tok_of_row = task_pm + MAXT;     // TROWS
    int* inv_row    = tok_of_row + TROWS; // NROWS
    float* top_w    = (float*)(inv_row + NROWS);  // NROWS
    float* w_of_row = top_w + NROWS;              // TROWS

    // ---- 1. dtype conversions (+ weight transposes to [N][K]) ----
    conv_x<<<(NTOK * HIDDEN) / (256 * 4), 256, 0, stream>>>(x, xb);
    tconv64<<<dim3(INTER / 32, HIDDEN / 64, NEXP), 256, 0, stream>>>(
        wg, wgT, HIDDEN, INTER, (long)HIDDEN * INTER, (long)INTER * HIDDEN);
    tconv64<<<dim3(INTER / 32, HIDDEN / 64, NEXP), 256, 0, stream>>>(
        wu, wuT, HIDDEN, INTER, (long)HIDDEN * INTER, (long)INTER * HIDDEN);
    tconv64<<<dim3(SINTER / 32, HIDDEN / 64, 1), 256, 0, stream>>>(
        swg, wgT + (size_t)8 * INTER * HIDDEN, HIDDEN, SINTER, 0, 0);
    tconv64<<<dim3(SINTER / 32, HIDDEN / 64, 1), 256, 0, stream>>>(
        swu, wuT + (size_t)8 * INTER * HIDDEN, HIDDEN, SINTER, 0, 0);
    tconv64<<<dim3(HIDDEN / 32, INTER / 64, NEXP), 256, 0, stream>>>(
        wd, wdT, INTER, HIDDEN, (long)INTER * HIDDEN, (long)HIDDEN * INTER);
    tconv64<<<dim3(HIDDEN / 32, INTER / 64, 2), 256, 0, stream>>>(
        swd, wdT + (size_t)8 * HIDDEN * INTER, INTER, HIDDEN,
        (long)INTER * HIDDEN, (long)HIDDEN * INTER);

    // ---- 2. gate + routing ----
    gate_kernel<<<NTOK, 64, 0, stream>>>(x, gw, top_i, top_w);
    hipMemsetAsync(cnt, 0, 8 * sizeof(int), stream);
    assign_kernel<<<NROWS / 256, 256, 0, stream>>>(top_i, cnt, rnk);
    scan_kernel<<<1, 1, 0, stream>>>(cnt, offs2, cnt2, task_pm);
    fill_kernel<<<NROWS / 256, 256, 0, stream>>>(top_i, top_w, rnk, offs2,
                                                 tok_of_row, w_of_row, inv_row);
    fill_shared<<<NROWS / 256, 256, 0, stream>>>(tok_of_row);

    // ---- 3. grouped SwiGLU GEMMs (dense 1-D swizzled grids) ----
    gemm_gu<<<MAXT * (INTER / 128), 256, 0, stream>>>(
        xb, wgT, wuT, act, tok_of_row, offs2, cnt2, task_pm);
    gemm_down<<<MAXT * (HIDDEN / 256), 256, 0, stream>>>(
        act, wdT, part, offs2, cnt2, task_pm);
    combine_kernel<<<NTOK, 256, 0, stream>>>(part, inv_row, w_of_row, out);
}